// Round 6
// baseline (230.023 us; speedup 1.0000x reference)
//
#include <hip/hip_runtime.h>
#include <hip/hip_bf16.h>
#include <math.h>

#define Hh 128   // hidden
#define Nn 32    // docs
#define Ll 128   // doc_len
#define W1S 384  // 3H
#define PAD 136  // bf16 elems per LDS row (272B stride, 16B-aligned)

typedef __attribute__((ext_vector_type(8))) short short8;
typedef __attribute__((ext_vector_type(4))) float floatx4;

__device__ __forceinline__ unsigned short f2bf(float x) {
  __hip_bfloat16 h = __float2bfloat16(x);
  return __builtin_bit_cast(unsigned short, h);
}
__device__ __forceinline__ short8 pack8(float4 a, float4 b) {
  short8 r;
  r[0] = (short)f2bf(a.x); r[1] = (short)f2bf(a.y);
  r[2] = (short)f2bf(a.z); r[3] = (short)f2bf(a.w);
  r[4] = (short)f2bf(b.x); r[5] = (short)f2bf(b.y);
  r[6] = (short)f2bf(b.z); r[7] = (short)f2bf(b.w);
  return r;
}
__device__ __forceinline__ void mul4(float4& a, const float4& b) {
  a.x *= b.x; a.y *= b.y; a.z *= b.z; a.w *= b.w;
}

// grid 128: n = bid&31 (XCD-aligned with k_main), s = bid>>5 (j-slice of 32).
// Computes: ent[n] (redundant x4), Bt'[n, s*32..+32, :] = (doc*ent)@W1b^T + b1,
// and docb (bf16 doc) rows n*128+s*32..+32.   [R4-proven]
__launch_bounds__(256, 2)
__global__ void k_prep(const float* __restrict__ wei, const int* __restrict__ wmask,
                       const float* __restrict__ doc, const float* __restrict__ W1,
                       const float* __restrict__ b1,
                       float* __restrict__ Bt, short* __restrict__ docb) {
  __shared__ __align__(16) short Wb[Hh * PAD];   // bf16(W1b) full
  __shared__ __align__(16) short Xs[32 * PAD];   // bf16(doc_slice * ent)
  __shared__ __align__(16) float red[2][Hh];

  int bid = blockIdx.x;
  int n = bid & 31, s = bid >> 5;
  int tid = threadIdx.x;
  const float* docn = doc + (size_t)n * Ll * Hh;
  int e8 = (tid & 15) * 8, rsub = tid >> 4;

  // phase A: stage W1b, ent partials, write bf16 doc slice
#pragma unroll
  for (int p = 0; p < 8; ++p) {
    int row = p * 16 + rsub;
    const float4* wp = (const float4*)(W1 + (size_t)row * W1S + Hh + e8);
    *(short8*)(Wb + row * PAD + e8) = pack8(wp[0], wp[1]);
  }
  {
    int e = tid & 127, half = tid >> 7;
    const float* wp = wei + (size_t)n * Ll * Hh + (size_t)half * 64 * Hh + e;
    const int* mp = wmask + n * Ll + half * 64;
    float a = 0.f;
#pragma unroll 8
    for (int l = 0; l < 64; ++l) a = fmaf((float)mp[l], wp[(size_t)l * Hh], a);
    red[half][e] = a;
  }
  {
    int row = s * 32 + (tid >> 3), c16 = (tid & 7) * 16;
    const float4* dp = (const float4*)(docn + (size_t)row * Hh + c16);
    float4 d0 = dp[0], d1 = dp[1], d2 = dp[2], d3 = dp[3];
    short* ob = docb + ((size_t)n * Ll + row) * Hh + c16;
    *(short8*)(ob) = pack8(d0, d1);
    *(short8*)(ob + 8) = pack8(d2, d3);
  }
  __syncthreads();

  // phase B: stage Xs rows (doc slice * ent)
  float4 ent0, ent1;
  {
    float e0v[8];
#pragma unroll
    for (int i = 0; i < 8; ++i) e0v[i] = red[0][e8 + i] + red[1][e8 + i];
    ent0 = make_float4(e0v[0], e0v[1], e0v[2], e0v[3]);
    ent1 = make_float4(e0v[4], e0v[5], e0v[6], e0v[7]);
  }
#pragma unroll
  for (int p = 0; p < 2; ++p) {
    int row = p * 16 + rsub;  // local 0..31
    const float4* dp = (const float4*)(docn + (size_t)(s * 32 + row) * Hh + e8);
    float4 a = dp[0], b = dp[1];
    mul4(a, ent0); mul4(b, ent1);
    *(short8*)(Xs + row * PAD + e8) = pack8(a, b);
  }
  __syncthreads();

  // GEMM: rows 32 (m), g partitioned by wave (32 each)
  int lane = tid & 63, w = tid >> 6;
  int l15 = lane & 15, quad = lane >> 4;
  floatx4 acc[2][2];
#pragma unroll
  for (int mt = 0; mt < 2; ++mt)
#pragma unroll
    for (int nt = 0; nt < 2; ++nt) acc[mt][nt] = (floatx4){0.f, 0.f, 0.f, 0.f};
#pragma unroll
  for (int e0 = 0; e0 < Hh; e0 += 32) {
    int eo = e0 + quad * 8;
    short8 af[2], bfr[2];
#pragma unroll
    for (int mt = 0; mt < 2; ++mt)
      af[mt] = *(const short8*)(Xs + (mt * 16 + l15) * PAD + eo);
#pragma unroll
    for (int nt = 0; nt < 2; ++nt)
      bfr[nt] = *(const short8*)(Wb + (w * 32 + nt * 16 + l15) * PAD + eo);
#pragma unroll
    for (int mt = 0; mt < 2; ++mt)
#pragma unroll
      for (int nt = 0; nt < 2; ++nt)
        acc[mt][nt] = __builtin_amdgcn_mfma_f32_16x16x32_bf16(af[mt], bfr[nt], acc[mt][nt], 0, 0, 0);
  }
  float* btn = Bt + (size_t)n * Ll * Hh;
  float b1g[2];
#pragma unroll
  for (int nt = 0; nt < 2; ++nt) b1g[nt] = b1[w * 32 + nt * 16 + l15];
#pragma unroll
  for (int mt = 0; mt < 2; ++mt)
#pragma unroll
    for (int nt = 0; nt < 2; ++nt)
#pragma unroll
      for (int r = 0; r < 4; ++r) {
        int j = s * 32 + mt * 16 + quad * 4 + r;
        btn[(size_t)j * Hh + w * 32 + nt * 16 + l15] = acc[mt][nt][r] + b1g[nt];
      }
}

// One block per (n,j), n = bid&31 (XCD swizzle). Two accumulating GEMMs into the
// same acc: pre[k,g] = doc_bf . (W1a*dj)_bf  +  doc_bf . (W1c*q)_bf, then
// + Bt'[j,g]; tanh; w2-dot (cross-wave g-reduce); masked softmax; weighted doc sum.
// NOTE: (256,2) not (256,4) — the R4 (256,4) clamp forced VGPR=64 and spilled
// ~23 KB/block to scratch (47 MB FETCH / 95 MB WRITE). 37.4 KB LDS + VGPR<=128
// gives 4 blocks/CU without any clamp.
__launch_bounds__(256, 2)
__global__ void k_main(const float* __restrict__ doc, const int* __restrict__ dmask,
                       const float* __restrict__ W1, const float* __restrict__ w2,
                       const float* __restrict__ b2, const float* __restrict__ q,
                       const float* __restrict__ Bt, const short* __restrict__ docb,
                       float* __restrict__ out) {
  __shared__ __align__(16) short As[Hh * PAD];   // 34.8 KB, staged twice
  __shared__ __align__(16) float scp[4][Ll];     // per-wave score partials
  __shared__ __align__(16) float scw[Ll];        // softmax weights

  int bid = blockIdx.x;
  int n = bid & 31, j = bid >> 5;
  int tid = threadIdx.x;
  const float* docn = doc + (size_t)n * Ll * Hh;
  size_t orow = ((size_t)n * Ll + j) * Hh;

  if (dmask[n * Ll + j] == 0) {   // fully-masked row -> exact zeros (~50% of blocks)
    if (tid < Hh) out[orow + tid] = 0.f;
    return;
  }

  int e8 = (tid & 15) * 8, rsub = tid >> 4;
  const float4* djp = (const float4*)(docn + (size_t)j * Hh + e8);
  float4 dj0 = djp[0], dj1 = djp[1];

  // stage As1 = bf16(W1a * dj)
#pragma unroll
  for (int p = 0; p < 8; ++p) {
    int row = p * 16 + rsub;
    const float4* wp = (const float4*)(W1 + (size_t)row * W1S + e8);
    float4 a = wp[0], b = wp[1];
    mul4(a, dj0); mul4(b, dj1);
    *(short8*)(As + row * PAD + e8) = pack8(a, b);
  }
  __syncthreads();

  int lane = tid & 63, w = tid >> 6;
  int l15 = lane & 15, quad = lane >> 4;
  const short* dbn = docb + (size_t)n * Ll * Hh;

  floatx4 acc[8][2];  // [mt = k-tile][nt = g-subtile]
#pragma unroll
  for (int mt = 0; mt < 8; ++mt)
#pragma unroll
    for (int nt = 0; nt < 2; ++nt) acc[mt][nt] = (floatx4){0.f, 0.f, 0.f, 0.f};

  // GEMM1: A = doc_bf (global), B = As1 (LDS)
#pragma unroll
  for (int e0 = 0; e0 < Hh; e0 += 32) {
    int eo = e0 + quad * 8;
    short8 bfr[2];
#pragma unroll
    for (int nt = 0; nt < 2; ++nt)
      bfr[nt] = *(const short8*)(As + (w * 32 + nt * 16 + l15) * PAD + eo);
#pragma unroll
    for (int mt = 0; mt < 8; ++mt) {
      short8 af = *(const short8*)(dbn + (size_t)(mt * 16 + l15) * Hh + eo);
#pragma unroll
      for (int nt = 0; nt < 2; ++nt)
        acc[mt][nt] = __builtin_amdgcn_mfma_f32_16x16x32_bf16(af, bfr[nt], acc[mt][nt], 0, 0, 0);
    }
  }
  __syncthreads();

  // stage As2 = bf16(W1c * q)
  const float4* qp = (const float4*)(q + (size_t)(n >> 3) * Hh + e8);
  float4 q0 = qp[0], q1 = qp[1];
#pragma unroll
  for (int p = 0; p < 8; ++p) {
    int row = p * 16 + rsub;
    const float4* wp = (const float4*)(W1 + (size_t)row * W1S + 2 * Hh + e8);
    float4 a = wp[0], b = wp[1];
    mul4(a, q0); mul4(b, q1);
    *(short8*)(As + row * PAD + e8) = pack8(a, b);
  }
  __syncthreads();

  // GEMM2: accumulate Ct contribution into same acc
#pragma unroll
  for (int e0 = 0; e0 < Hh; e0 += 32) {
    int eo = e0 + quad * 8;
    short8 bfr[2];
#pragma unroll
    for (int nt = 0; nt < 2; ++nt)
      bfr[nt] = *(const short8*)(As + (w * 32 + nt * 16 + l15) * PAD + eo);
#pragma unroll
    for (int mt = 0; mt < 8; ++mt) {
      short8 af = *(const short8*)(dbn + (size_t)(mt * 16 + l15) * Hh + eo);
#pragma unroll
      for (int nt = 0; nt < 2; ++nt)
        acc[mt][nt] = __builtin_amdgcn_mfma_f32_16x16x32_bf16(af, bfr[nt], acc[mt][nt], 0, 0, 0);
    }
  }

  // epilogue: tanh(pre + Bt'[j,g]) . w2 over this wave's 32 g, reduce over l15
  const float c2 = 2.885390081777927f;  // 2*log2(e)
  const float* btrow = Bt + orow;
  float bbc[2], w2r[2];
#pragma unroll
  for (int nt = 0; nt < 2; ++nt) {
    int g = w * 32 + nt * 16 + l15;
    bbc[nt] = btrow[g] * c2;   // b1 already folded in k_prep
    w2r[nt] = w2[g];
  }
#pragma unroll
  for (int mt = 0; mt < 8; ++mt) {
#pragma unroll
    for (int r = 0; r < 4; ++r) {
      float p = 0.f;
#pragma unroll
      for (int nt = 0; nt < 2; ++nt) {
        float a2 = fmaf(acc[mt][nt][r], c2, bbc[nt]);
        float e = exp2f(a2);
        float th = fmaf(-2.f, __builtin_amdgcn_rcpf(e + 1.f), 1.f);
        p = fmaf(th, w2r[nt], p);
      }
      p += __shfl_xor(p, 1);
      p += __shfl_xor(p, 2);
      p += __shfl_xor(p, 4);
      p += __shfl_xor(p, 8);
      if (l15 == 0) scp[w][mt * 16 + quad * 4 + r] = p;
    }
  }
  __syncthreads();

  // masked softmax over k (redundant per wave; no extra barriers)
  {
    float b2v = b2[0];
    const float inv = 0.088388347648318447f;  // 1/sqrt(128)
    const int* dmn = dmask + n * Ll;
    int k0 = lane, k1 = lane + 64;
    float s0 = scp[0][k0] + scp[1][k0] + scp[2][k0] + scp[3][k0];
    float s1 = scp[0][k1] + scp[1][k1] + scp[2][k1] + scp[3][k1];
    int m0 = dmn[k0], m1 = dmn[k1];
    s0 = m0 ? (s0 + b2v) * inv : -1e9f;
    s1 = m1 ? (s1 + b2v) * inv : -1e9f;
    float mx = fmaxf(s0, s1);
#pragma unroll
    for (int off = 32; off; off >>= 1) mx = fmaxf(mx, __shfl_xor(mx, off));
    float ex0 = __expf(s0 - mx), ex1 = __expf(s1 - mx);
    float sm = ex0 + ex1;
#pragma unroll
    for (int off = 32; off; off >>= 1) sm += __shfl_xor(sm, off);
    float rden = 1.f / sm;
    scw[k0] = m0 ? ex0 * rden : 0.f;   // all 4 waves write identical values
    scw[k1] = m1 ? ex1 * rden : 0.f;
  }
  __syncthreads();

  // out[j,h] = sum_k w[k] * doc[n,k,h]   (fp32 doc for accuracy)
  float* ored = (float*)scp;  // scp dead; reuse as [2][128]
  int half = tid >> 7, h = tid & 127;
  const float* dbase = docn + (size_t)half * 64 * Hh + h;
  float o = 0.f;
#pragma unroll 8
  for (int kk = 0; kk < 64; ++kk)
    o = fmaf(scw[half * 64 + kk], dbase[(size_t)kk * Hh], o);
  ored[half * Hh + h] = o;
  __syncthreads();
  if (tid < Ll) out[orow + tid] = ored[tid] + ored[Hh + tid];
}

extern "C" void kernel_launch(void* const* d_in, const int* in_sizes, int n_in,
                              void* d_out, int out_size, void* d_ws, size_t ws_size,
                              hipStream_t stream) {
  const float* wei   = (const float*)d_in[0];
  const int*   wmask = (const int*)d_in[1];
  const float* doc   = (const float*)d_in[2];
  const int*   dmask = (const int*)d_in[3];
  const float* q     = (const float*)d_in[4];
  const float* W1    = (const float*)d_in[5];
  const float* b1    = (const float*)d_in[6];
  const float* w2    = (const float*)d_in[7];
  const float* b2    = (const float*)d_in[8];
  float* out = (float*)d_out;

  float* ws   = (float*)d_ws;
  float* Bt   = ws;                              // N*L*H fp32 (2.10 MB), b1 folded
  short* docb = (short*)(Bt + (size_t)Nn * Ll * Hh);  // N*L*H bf16 (1.05 MB)

  k_prep<<<4 * Nn, 256, 0, stream>>>(wei, wmask, doc, W1, b1, Bt, docb);
  k_main<<<Nn * Ll, 256, 0, stream>>>(doc, dmask, W1, w2, b2, q, Bt, docb, out);
}

// Round 7
// 181.053 us; speedup vs baseline: 1.2705x; 1.2705x over previous
//
#include <hip/hip_runtime.h>
#include <hip/hip_bf16.h>
#include <math.h>

#define Hh 128   // hidden
#define Nn 32    // docs
#define Ll 128   // doc_len
#define W1S 384  // 3H
#define PAD 136  // bf16 elems per LDS row (272B stride, 16B-aligned)

typedef __attribute__((ext_vector_type(8))) short short8;
typedef __attribute__((ext_vector_type(4))) float floatx4;

__device__ __forceinline__ unsigned short f2bf(float x) {
  __hip_bfloat16 h = __float2bfloat16(x);
  return __builtin_bit_cast(unsigned short, h);
}
__device__ __forceinline__ float bf2f(short s) {
  unsigned int u = ((unsigned int)(unsigned short)s) << 16;
  return __builtin_bit_cast(float, u);
}
__device__ __forceinline__ short8 pack8(float4 a, float4 b) {
  short8 r;
  r[0] = (short)f2bf(a.x); r[1] = (short)f2bf(a.y);
  r[2] = (short)f2bf(a.z); r[3] = (short)f2bf(a.w);
  r[4] = (short)f2bf(b.x); r[5] = (short)f2bf(b.y);
  r[6] = (short)f2bf(b.z); r[7] = (short)f2bf(b.w);
  return r;
}
__device__ __forceinline__ void mul4(float4& a, const float4& b) {
  a.x *= b.x; a.y *= b.y; a.z *= b.z; a.w *= b.w;
}

// grid 64: n = bid>>1, which = bid&1. which==0: Bt=(doc*ent)@W1b^T + b1 (fp32);
// which==1: Ct=(doc*q)@W1c^T (bf16). Both: write their half of docb = bf16(doc).
__launch_bounds__(256, 2)
__global__ void k_prep(const float* __restrict__ wei, const int* __restrict__ wmask,
                       const float* __restrict__ doc, const float* __restrict__ q,
                       const float* __restrict__ W1, const float* __restrict__ b1,
                       float* __restrict__ Bt, unsigned short* __restrict__ Ctb,
                       short* __restrict__ docb) {
  __shared__ __align__(16) short Xs[Hh * PAD];  // bf16(doc * ms)
  __shared__ __align__(16) short Ws[Hh * PAD];  // bf16(W1b or W1c)
  __shared__ __align__(16) float red[2][Hh];
  __shared__ __align__(16) float ms[Hh];

  int bid = blockIdx.x;
  int n = bid >> 1, which = bid & 1;
  int tid = threadIdx.x;
  const float* docn = doc + (size_t)n * Ll * Hh;
  int e8 = (tid & 15) * 8, rsub = tid >> 4;

  // phase A: ent partials (which==0) / q (which==1); stage Ws; write docb half
  if (which == 0) {
    int e = tid & 127, half = tid >> 7;
    const float* wp = wei + (size_t)n * Ll * Hh + (size_t)half * 64 * Hh + e;
    const int* mp = wmask + n * Ll + half * 64;
    float a = 0.f;
#pragma unroll 8
    for (int l = 0; l < 64; ++l) a = fmaf((float)mp[l], wp[(size_t)l * Hh], a);
    red[half][e] = a;
  } else {
    if (tid < Hh) ms[tid] = q[(size_t)(n >> 3) * Hh + tid];
  }
  {
    int row = which * 64 + (tid >> 2);
    int c32 = (tid & 3) * 32;
    const float4* dp = (const float4*)(docn + (size_t)row * Hh + c32);
    short* ob = docb + ((size_t)n * Ll + row) * Hh + c32;
#pragma unroll
    for (int i = 0; i < 4; ++i)
      *(short8*)(ob + i * 8) = pack8(dp[2 * i], dp[2 * i + 1]);
  }
  const float* wbase = W1 + Hh + which * Hh;
#pragma unroll
  for (int p = 0; p < 8; ++p) {
    int row = p * 16 + rsub;
    const float4* wp = (const float4*)(wbase + (size_t)row * W1S + e8);
    *(short8*)(Ws + row * PAD + e8) = pack8(wp[0], wp[1]);
  }
  __syncthreads();
  if (which == 0 && tid < Hh) ms[tid] = red[0][tid] + red[1][tid];
  __syncthreads();

  // phase B: Xs = bf16(doc * ms)
  {
    const float4* mp4 = (const float4*)(ms + e8);
    float4 m0 = mp4[0], m1 = mp4[1];
#pragma unroll
    for (int p = 0; p < 8; ++p) {
      int row = p * 16 + rsub;
      const float4* dp = (const float4*)(docn + (size_t)row * Hh + e8);
      float4 a = dp[0], b = dp[1];
      mul4(a, m0); mul4(b, m1);
      *(short8*)(Xs + row * PAD + e8) = pack8(a, b);
    }
  }
  __syncthreads();

  // GEMM (proven): waves own 32 k-rows, full 128 g
  int lane = tid & 63, w = tid >> 6;
  int l15 = lane & 15, quad = lane >> 4;
  floatx4 acc[2][8];
#pragma unroll
  for (int mt = 0; mt < 2; ++mt)
#pragma unroll
    for (int nt = 0; nt < 8; ++nt) acc[mt][nt] = (floatx4){0.f, 0.f, 0.f, 0.f};
#pragma unroll
  for (int e0 = 0; e0 < Hh; e0 += 32) {
    int eo = e0 + quad * 8;
    short8 af[2], bfr[8];
    af[0] = *(const short8*)(Xs + (w * 32 + l15) * PAD + eo);
    af[1] = *(const short8*)(Xs + (w * 32 + 16 + l15) * PAD + eo);
#pragma unroll
    for (int nt = 0; nt < 8; ++nt)
      bfr[nt] = *(const short8*)(Ws + (nt * 16 + l15) * PAD + eo);
#pragma unroll
    for (int mt = 0; mt < 2; ++mt)
#pragma unroll
      for (int nt = 0; nt < 8; ++nt)
        acc[mt][nt] = __builtin_amdgcn_mfma_f32_16x16x32_bf16(af[mt], bfr[nt], acc[mt][nt], 0, 0, 0);
  }
  if (which == 0) {
    float* outp = Bt + (size_t)n * Ll * Hh;
    float addv[8];
#pragma unroll
    for (int nt = 0; nt < 8; ++nt) addv[nt] = b1[nt * 16 + l15];
#pragma unroll
    for (int mt = 0; mt < 2; ++mt)
#pragma unroll
      for (int nt = 0; nt < 8; ++nt)
#pragma unroll
        for (int r = 0; r < 4; ++r) {
          int k = w * 32 + mt * 16 + quad * 4 + r;
          outp[(size_t)k * Hh + nt * 16 + l15] = acc[mt][nt][r] + addv[nt];
        }
  } else {
    unsigned short* outp = Ctb + (size_t)n * Ll * Hh;
#pragma unroll
    for (int mt = 0; mt < 2; ++mt)
#pragma unroll
      for (int nt = 0; nt < 8; ++nt)
#pragma unroll
        for (int r = 0; r < 4; ++r) {
          int k = w * 32 + mt * 16 + quad * 4 + r;
          outp[(size_t)k * Hh + nt * 16 + l15] = f2bf(acc[mt][nt][r]);
        }
  }
}

// One block per (n, j-quad); n = bid&31 (XCD swizzle). W1a bf16 staged in LDS once;
// A = raw bf16 doc frags in REGISTERS (gathered once per block); per j: fold dj into
// A-frags in registers (no LDS restage, no gather), GEMM, epilogue(+Bt fp32 +Ct bf16),
// 1 barrier/j, redundant softmax; fused 4-j weighted doc-sum.
__launch_bounds__(256, 3)
__global__ void k_main(const float* __restrict__ doc, const int* __restrict__ dmask,
                       const float* __restrict__ W1, const float* __restrict__ w2,
                       const float* __restrict__ b2,
                       const float* __restrict__ Bt, const unsigned short* __restrict__ Ctb,
                       const short* __restrict__ docb, float* __restrict__ out) {
  __shared__ __align__(16) short Wa[Hh * PAD];   // bf16(W1a)  34.8 KB
  __shared__ __align__(16) float sc[4][Ll];      // per-jv raw scores
  __shared__ __align__(16) float scwq[Ll][4];    // softmax weights [k][jv]
  __shared__ __align__(16) float ored[2][4][Hh]; // weighted-sum partials

  int bid = blockIdx.x;
  int n = bid & 31, jq = bid >> 5;
  int tid = threadIdx.x;
  const float* docn = doc + (size_t)n * Ll * Hh;
  const short* dbn = docb + (size_t)n * Ll * Hh;
  const int* dmn = dmask + n * Ll;
  int e8 = (tid & 15) * 8, rsub = tid >> 4;

  // stage Wa = bf16(W1a) once
#pragma unroll
  for (int p = 0; p < 8; ++p) {
    int row = p * 16 + rsub;
    const float4* wp = (const float4*)(W1 + (size_t)row * W1S + e8);
    *(short8*)(Wa + row * PAD + e8) = pack8(wp[0], wp[1]);
  }

  int lane = tid & 63, w = tid >> 6;
  int l15 = lane & 15, quad = lane >> 4;

  // A-frags (raw bf16 doc) once per block: wave owns k-rows [32w, 32w+32)
  short8 afr[2][4];
#pragma unroll
  for (int mt = 0; mt < 2; ++mt)
#pragma unroll
    for (int c = 0; c < 4; ++c)
      afr[mt][c] = *(const short8*)(dbn + (size_t)(w * 32 + mt * 16 + l15) * Hh + c * 32 + quad * 8);

  float w2r[8];
#pragma unroll
  for (int nt = 0; nt < 8; ++nt) w2r[nt] = w2[nt * 16 + l15];
  int m0 = dmn[lane], m1 = dmn[lane + 64];
  float b2v = b2[0];
  const float c2 = 2.885390081777927f;      // 2*log2(e)
  const float inv = 0.088388347648318447f;  // 1/sqrt(128)
  const unsigned short* ctn = Ctb + (size_t)n * Ll * Hh;
  __syncthreads();

  for (int jv = 0; jv < 4; ++jv) {
    int j = jq * 4 + jv;
    if (dmn[j] == 0) {            // block-uniform: fully-masked row -> zero weights
      if (tid < Ll) scwq[tid][jv] = 0.f;
      continue;
    }
    floatx4 acc[2][8];
#pragma unroll
    for (int mt = 0; mt < 2; ++mt)
#pragma unroll
      for (int nt = 0; nt < 8; ++nt) acc[mt][nt] = (floatx4){0.f, 0.f, 0.f, 0.f};

#pragma unroll
    for (int c = 0; c < 4; ++c) {
      int eo = c * 32 + quad * 8;
      short8 djs = *(const short8*)(dbn + (size_t)j * Hh + eo);
      float djf[8];
#pragma unroll
      for (int i = 0; i < 8; ++i) djf[i] = bf2f(djs[i]);
      short8 afs[2];
#pragma unroll
      for (int mt = 0; mt < 2; ++mt) {
        short8 r;
#pragma unroll
        for (int i = 0; i < 8; ++i) r[i] = (short)f2bf(bf2f(afr[mt][c][i]) * djf[i]);
        afs[mt] = r;
      }
      short8 bfr[8];
#pragma unroll
      for (int nt = 0; nt < 8; ++nt)
        bfr[nt] = *(const short8*)(Wa + (nt * 16 + l15) * PAD + eo);
#pragma unroll
      for (int mt = 0; mt < 2; ++mt)
#pragma unroll
        for (int nt = 0; nt < 8; ++nt)
          acc[mt][nt] = __builtin_amdgcn_mfma_f32_16x16x32_bf16(afs[mt], bfr[nt], acc[mt][nt], 0, 0, 0);
    }

    // epilogue: tanh(acc + Ct[k,g] + Bt'[j,g]) . w2 -> sc[jv][k]  (wave-local k)
    const float* btrow = Bt + ((size_t)n * Ll + j) * Hh;
    float bbc[8];
#pragma unroll
    for (int nt = 0; nt < 8; ++nt) bbc[nt] = btrow[nt * 16 + l15] * c2;  // b1 folded
#pragma unroll
    for (int mt = 0; mt < 2; ++mt) {
#pragma unroll
      for (int r = 0; r < 4; ++r) {
        int k = w * 32 + mt * 16 + quad * 4 + r;
        const unsigned short* ctp = ctn + (size_t)k * Hh + l15;
        float p = 0.f;
#pragma unroll
        for (int nt = 0; nt < 8; ++nt) {
          float s = acc[mt][nt][r] + bf2f((short)ctp[nt * 16]);
          float a2 = fmaf(s, c2, bbc[nt]);
          float e = exp2f(a2);
          float th = fmaf(-2.f, __builtin_amdgcn_rcpf(e + 1.f), 1.f);
          p = fmaf(th, w2r[nt], p);
        }
        p += __shfl_xor(p, 1);
        p += __shfl_xor(p, 2);
        p += __shfl_xor(p, 4);
        p += __shfl_xor(p, 8);
        if (l15 == 0) sc[jv][k] = p;
      }
    }
    __syncthreads();   // the only barrier per j

    // redundant per-wave masked softmax -> scwq[.][jv]
    {
      float s0 = m0 ? (sc[jv][lane] + b2v) * inv : -1e9f;
      float s1 = m1 ? (sc[jv][lane + 64] + b2v) * inv : -1e9f;
      float mx = fmaxf(s0, s1);
#pragma unroll
      for (int off = 32; off; off >>= 1) mx = fmaxf(mx, __shfl_xor(mx, off));
      float ex0 = __expf(s0 - mx), ex1 = __expf(s1 - mx);
      float sm = ex0 + ex1;
#pragma unroll
      for (int off = 32; off; off >>= 1) sm += __shfl_xor(sm, off);
      float rden = 1.f / sm;
      scwq[lane][jv] = m0 ? ex0 * rden : 0.f;      // identical across waves
      scwq[lane + 64][jv] = m1 ? ex1 * rden : 0.f;
    }
  }
  __syncthreads();

  // fused weighted sum: out[j,h] = sum_k scwq[k][jv] * doc[n,k,h], 4 j's at once
  int half = tid >> 7, h = tid & 127;
  const float* dbase = docn + (size_t)half * 64 * Hh + h;
  float o0 = 0.f, o1 = 0.f, o2 = 0.f, o3 = 0.f;
#pragma unroll 8
  for (int kk = 0; kk < 64; ++kk) {
    float d = dbase[(size_t)kk * Hh];
    float4 wv = *(const float4*)&scwq[half * 64 + kk][0];
    o0 = fmaf(wv.x, d, o0); o1 = fmaf(wv.y, d, o1);
    o2 = fmaf(wv.z, d, o2); o3 = fmaf(wv.w, d, o3);
  }
  ored[half][0][h] = o0; ored[half][1][h] = o1;
  ored[half][2][h] = o2; ored[half][3][h] = o3;
  __syncthreads();
  if (tid < Ll) {
#pragma unroll
    for (int jv = 0; jv < 4; ++jv)
      out[((size_t)n * Ll + jq * 4 + jv) * Hh + tid] = ored[0][jv][tid] + ored[1][jv][tid];
  }
}

extern "C" void kernel_launch(void* const* d_in, const int* in_sizes, int n_in,
                              void* d_out, int out_size, void* d_ws, size_t ws_size,
                              hipStream_t stream) {
  const float* wei   = (const float*)d_in[0];
  const int*   wmask = (const int*)d_in[1];
  const float* doc   = (const float*)d_in[2];
  const int*   dmask = (const int*)d_in[3];
  const float* q     = (const float*)d_in[4];
  const float* W1    = (const float*)d_in[5];
  const float* b1    = (const float*)d_in[6];
  const float* w2    = (const float*)d_in[7];
  const float* b2    = (const float*)d_in[8];
  float* out = (float*)d_out;

  float* ws = (float*)d_ws;
  float*          Bt   = ws;                                        // N*L*H fp32 (2.10 MB), b1 folded
  unsigned short* Ctb  = (unsigned short*)(Bt + (size_t)Nn * Ll * Hh);   // N*L*H bf16 (1.05 MB)
  short*          docb = (short*)(Ctb + (size_t)Nn * Ll * Hh);      // N*L*H bf16 (1.05 MB) => 4.19 MB total

  k_prep<<<2 * Nn, 256, 0, stream>>>(wei, wmask, doc, q, W1, b1, Bt, Ctb, docb);
  k_main<<<Nn * Ll / 4, 256, 0, stream>>>(doc, dmask, W1, w2, b2, Bt, Ctb, docb, out);
}

// Round 8
// 136.470 us; speedup vs baseline: 1.6855x; 1.3267x over previous
//
#include <hip/hip_runtime.h>
#include <hip/hip_bf16.h>
#include <math.h>

#define Hh 128   // hidden
#define Nn 32    // docs
#define Ll 128   // doc_len
#define W1S 384  // 3H
#define PAD 136  // bf16 elems per LDS row (272B stride, 16B-aligned)

typedef __attribute__((ext_vector_type(8))) short short8;
typedef __attribute__((ext_vector_type(4))) float floatx4;

__device__ __forceinline__ unsigned short f2bf(float x) {
  __hip_bfloat16 h = __float2bfloat16(x);
  return __builtin_bit_cast(unsigned short, h);
}
__device__ __forceinline__ float bf2f(short s) {
  unsigned int u = ((unsigned int)(unsigned short)s) << 16;
  return __builtin_bit_cast(float, u);
}
__device__ __forceinline__ short8 pack8(float4 a, float4 b) {
  short8 r;
  r[0] = (short)f2bf(a.x); r[1] = (short)f2bf(a.y);
  r[2] = (short)f2bf(a.z); r[3] = (short)f2bf(a.w);
  r[4] = (short)f2bf(b.x); r[5] = (short)f2bf(b.y);
  r[6] = (short)f2bf(b.z); r[7] = (short)f2bf(b.w);
  return r;
}
__device__ __forceinline__ void mul4(float4& a, const float4& b) {
  a.x *= b.x; a.y *= b.y; a.z *= b.z; a.w *= b.w;
}

// grid 64: n = bid>>1, which = bid&1. which==0: Bt=(doc*ent)@W1b^T + b1 (fp32);
// which==1: Ct=(doc*q)@W1c^T (bf16). Both: write their half of docb = bf16(doc).
__launch_bounds__(256, 2)
__global__ void k_prep(const float* __restrict__ wei, const int* __restrict__ wmask,
                       const float* __restrict__ doc, const float* __restrict__ q,
                       const float* __restrict__ W1, const float* __restrict__ b1,
                       float* __restrict__ Bt, unsigned short* __restrict__ Ctb,
                       short* __restrict__ docb) {
  __shared__ __align__(16) short Xs[Hh * PAD];  // bf16(doc * ms)
  __shared__ __align__(16) short Ws[Hh * PAD];  // bf16(W1b or W1c)
  __shared__ __align__(16) float red[2][Hh];
  __shared__ __align__(16) float ms[Hh];

  int bid = blockIdx.x;
  int n = bid >> 1, which = bid & 1;
  int tid = threadIdx.x;
  const float* docn = doc + (size_t)n * Ll * Hh;
  int e8 = (tid & 15) * 8, rsub = tid >> 4;

  // phase A: ent partials (which==0) / q (which==1); stage Ws; write docb half
  if (which == 0) {
    int e = tid & 127, half = tid >> 7;
    const float* wp = wei + (size_t)n * Ll * Hh + (size_t)half * 64 * Hh + e;
    const int* mp = wmask + n * Ll + half * 64;
    float a = 0.f;
#pragma unroll 8
    for (int l = 0; l < 64; ++l) a = fmaf((float)mp[l], wp[(size_t)l * Hh], a);
    red[half][e] = a;
  } else {
    if (tid < Hh) ms[tid] = q[(size_t)(n >> 3) * Hh + tid];
  }
  {
    int row = which * 64 + (tid >> 2);
    int c32 = (tid & 3) * 32;
    const float4* dp = (const float4*)(docn + (size_t)row * Hh + c32);
    short* ob = docb + ((size_t)n * Ll + row) * Hh + c32;
#pragma unroll
    for (int i = 0; i < 4; ++i)
      *(short8*)(ob + i * 8) = pack8(dp[2 * i], dp[2 * i + 1]);
  }
  const float* wbase = W1 + Hh + which * Hh;
#pragma unroll
  for (int p = 0; p < 8; ++p) {
    int row = p * 16 + rsub;
    const float4* wp = (const float4*)(wbase + (size_t)row * W1S + e8);
    *(short8*)(Ws + row * PAD + e8) = pack8(wp[0], wp[1]);
  }
  __syncthreads();
  if (which == 0 && tid < Hh) ms[tid] = red[0][tid] + red[1][tid];
  __syncthreads();

  // phase B: Xs = bf16(doc * ms)
  {
    const float4* mp4 = (const float4*)(ms + e8);
    float4 m0 = mp4[0], m1 = mp4[1];
#pragma unroll
    for (int p = 0; p < 8; ++p) {
      int row = p * 16 + rsub;
      const float4* dp = (const float4*)(docn + (size_t)row * Hh + e8);
      float4 a = dp[0], b = dp[1];
      mul4(a, m0); mul4(b, m1);
      *(short8*)(Xs + row * PAD + e8) = pack8(a, b);
    }
  }
  __syncthreads();

  // GEMM (proven): waves own 32 k-rows, full 128 g
  int lane = tid & 63, w = tid >> 6;
  int l15 = lane & 15, quad = lane >> 4;
  floatx4 acc[2][8];
#pragma unroll
  for (int mt = 0; mt < 2; ++mt)
#pragma unroll
    for (int nt = 0; nt < 8; ++nt) acc[mt][nt] = (floatx4){0.f, 0.f, 0.f, 0.f};
#pragma unroll
  for (int e0 = 0; e0 < Hh; e0 += 32) {
    int eo = e0 + quad * 8;
    short8 af[2], bfr[8];
    af[0] = *(const short8*)(Xs + (w * 32 + l15) * PAD + eo);
    af[1] = *(const short8*)(Xs + (w * 32 + 16 + l15) * PAD + eo);
#pragma unroll
    for (int nt = 0; nt < 8; ++nt)
      bfr[nt] = *(const short8*)(Ws + (nt * 16 + l15) * PAD + eo);
#pragma unroll
    for (int mt = 0; mt < 2; ++mt)
#pragma unroll
      for (int nt = 0; nt < 8; ++nt)
        acc[mt][nt] = __builtin_amdgcn_mfma_f32_16x16x32_bf16(af[mt], bfr[nt], acc[mt][nt], 0, 0, 0);
  }
  if (which == 0) {
    float* outp = Bt + (size_t)n * Ll * Hh;
    float addv[8];
#pragma unroll
    for (int nt = 0; nt < 8; ++nt) addv[nt] = b1[nt * 16 + l15];
#pragma unroll
    for (int mt = 0; mt < 2; ++mt)
#pragma unroll
      for (int nt = 0; nt < 8; ++nt)
#pragma unroll
        for (int r = 0; r < 4; ++r) {
          int k = w * 32 + mt * 16 + quad * 4 + r;
          outp[(size_t)k * Hh + nt * 16 + l15] = acc[mt][nt][r] + addv[nt];
        }
  } else {
    unsigned short* outp = Ctb + (size_t)n * Ll * Hh;
#pragma unroll
    for (int mt = 0; mt < 2; ++mt)
#pragma unroll
      for (int nt = 0; nt < 8; ++nt)
#pragma unroll
        for (int r = 0; r < 4; ++r) {
          int k = w * 32 + mt * 16 + quad * 4 + r;
          outp[(size_t)k * Hh + nt * 16 + l15] = f2bf(acc[mt][nt][r]);
        }
  }
}

// One block per (n, j-quad); n = bid&31 (XCD swizzle). W1a bf16 staged in LDS once;
// A = raw bf16 doc frags in REGISTERS (gathered once per block); per j: fold dj into
// A-frags in registers (no LDS restage, no gather), GEMM, epilogue(+Bt fp32 +Ct bf16),
// 1 barrier/j, redundant softmax; fused 4-j weighted doc-sum.
// NOTE: (256,2) NOT (256,3/4). Any tighter clamp under a 64-AGPR accumulator forces
// scratch spill (R4: VGPR=64, 95 MB WRITE; R7: VGPR=84, 56 MB WRITE). With 43 KB LDS
// the natural allocation can still give 2-3 blocks/CU.
__launch_bounds__(256, 2)
__global__ void k_main(const float* __restrict__ doc, const int* __restrict__ dmask,
                       const float* __restrict__ W1, const float* __restrict__ w2,
                       const float* __restrict__ b2,
                       const float* __restrict__ Bt, const unsigned short* __restrict__ Ctb,
                       const short* __restrict__ docb, float* __restrict__ out) {
  __shared__ __align__(16) short Wa[Hh * PAD];   // bf16(W1a)  34.8 KB
  __shared__ __align__(16) float sc[4][Ll];      // per-jv raw scores
  __shared__ __align__(16) float scwq[Ll][4];    // softmax weights [k][jv]
  __shared__ __align__(16) float ored[2][4][Hh]; // weighted-sum partials

  int bid = blockIdx.x;
  int n = bid & 31, jq = bid >> 5;
  int tid = threadIdx.x;
  const float* docn = doc + (size_t)n * Ll * Hh;
  const short* dbn = docb + (size_t)n * Ll * Hh;
  const int* dmn = dmask + n * Ll;
  int e8 = (tid & 15) * 8, rsub = tid >> 4;

  // stage Wa = bf16(W1a) once
#pragma unroll
  for (int p = 0; p < 8; ++p) {
    int row = p * 16 + rsub;
    const float4* wp = (const float4*)(W1 + (size_t)row * W1S + e8);
    *(short8*)(Wa + row * PAD + e8) = pack8(wp[0], wp[1]);
  }

  int lane = tid & 63, w = tid >> 6;
  int l15 = lane & 15, quad = lane >> 4;

  // A-frags (raw bf16 doc) once per block: wave owns k-rows [32w, 32w+32)
  short8 afr[2][4];
#pragma unroll
  for (int mt = 0; mt < 2; ++mt)
#pragma unroll
    for (int c = 0; c < 4; ++c)
      afr[mt][c] = *(const short8*)(dbn + (size_t)(w * 32 + mt * 16 + l15) * Hh + c * 32 + quad * 8);

  float w2r[8];
#pragma unroll
  for (int nt = 0; nt < 8; ++nt) w2r[nt] = w2[nt * 16 + l15];
  int m0 = dmn[lane], m1 = dmn[lane + 64];
  float b2v = b2[0];
  const float c2 = 2.885390081777927f;      // 2*log2(e)
  const float inv = 0.088388347648318447f;  // 1/sqrt(128)
  const unsigned short* ctn = Ctb + (size_t)n * Ll * Hh;
  __syncthreads();

  for (int jv = 0; jv < 4; ++jv) {
    int j = jq * 4 + jv;
    if (dmn[j] == 0) {            // block-uniform: fully-masked row -> zero weights
      if (tid < Ll) scwq[tid][jv] = 0.f;
      continue;
    }
    floatx4 acc[2][8];
#pragma unroll
    for (int mt = 0; mt < 2; ++mt)
#pragma unroll
      for (int nt = 0; nt < 8; ++nt) acc[mt][nt] = (floatx4){0.f, 0.f, 0.f, 0.f};

#pragma unroll
    for (int c = 0; c < 4; ++c) {
      int eo = c * 32 + quad * 8;
      short8 djs = *(const short8*)(dbn + (size_t)j * Hh + eo);
      float djf[8];
#pragma unroll
      for (int i = 0; i < 8; ++i) djf[i] = bf2f(djs[i]);
      short8 afs[2];
#pragma unroll
      for (int mt = 0; mt < 2; ++mt) {
        short8 r;
#pragma unroll
        for (int i = 0; i < 8; ++i) r[i] = (short)f2bf(bf2f(afr[mt][c][i]) * djf[i]);
        afs[mt] = r;
      }
      short8 bfr[8];
#pragma unroll
      for (int nt = 0; nt < 8; ++nt)
        bfr[nt] = *(const short8*)(Wa + (nt * 16 + l15) * PAD + eo);
#pragma unroll
      for (int mt = 0; mt < 2; ++mt)
#pragma unroll
        for (int nt = 0; nt < 8; ++nt)
          acc[mt][nt] = __builtin_amdgcn_mfma_f32_16x16x32_bf16(afs[mt], bfr[nt], acc[mt][nt], 0, 0, 0);
    }

    // epilogue: tanh(acc + Ct[k,g] + Bt'[j,g]) . w2 -> sc[jv][k]  (wave-local k)
    const float* btrow = Bt + ((size_t)n * Ll + j) * Hh;
    float bbc[8];
#pragma unroll
    for (int nt = 0; nt < 8; ++nt) bbc[nt] = btrow[nt * 16 + l15] * c2;  // b1 folded
#pragma unroll
    for (int mt = 0; mt < 2; ++mt) {
#pragma unroll
      for (int r = 0; r < 4; ++r) {
        int k = w * 32 + mt * 16 + quad * 4 + r;
        const unsigned short* ctp = ctn + (size_t)k * Hh + l15;
        float p = 0.f;
#pragma unroll
        for (int nt = 0; nt < 8; ++nt) {
          float s = acc[mt][nt][r] + bf2f((short)ctp[nt * 16]);
          float a2 = fmaf(s, c2, bbc[nt]);
          float e = exp2f(a2);
          float th = fmaf(-2.f, __builtin_amdgcn_rcpf(e + 1.f), 1.f);
          p = fmaf(th, w2r[nt], p);
        }
        p += __shfl_xor(p, 1);
        p += __shfl_xor(p, 2);
        p += __shfl_xor(p, 4);
        p += __shfl_xor(p, 8);
        if (l15 == 0) sc[jv][k] = p;
      }
    }
    __syncthreads();   // the only barrier per j

    // redundant per-wave masked softmax -> scwq[.][jv]
    {
      float s0 = m0 ? (sc[jv][lane] + b2v) * inv : -1e9f;
      float s1 = m1 ? (sc[jv][lane + 64] + b2v) * inv : -1e9f;
      float mx = fmaxf(s0, s1);
#pragma unroll
      for (int off = 32; off; off >>= 1) mx = fmaxf(mx, __shfl_xor(mx, off));
      float ex0 = __expf(s0 - mx), ex1 = __expf(s1 - mx);
      float sm = ex0 + ex1;
#pragma unroll
      for (int off = 32; off; off >>= 1) sm += __shfl_xor(sm, off);
      float rden = 1.f / sm;
      scwq[lane][jv] = m0 ? ex0 * rden : 0.f;      // identical across waves
      scwq[lane + 64][jv] = m1 ? ex1 * rden : 0.f;
    }
  }
  __syncthreads();

  // fused weighted sum: out[j,h] = sum_k scwq[k][jv] * doc[n,k,h], 4 j's at once
  int half = tid >> 7, h = tid & 127;
  const float* dbase = docn + (size_t)half * 64 * Hh + h;
  float o0 = 0.f, o1 = 0.f, o2 = 0.f, o3 = 0.f;
#pragma unroll 8
  for (int kk = 0; kk < 64; ++kk) {
    float d = dbase[(size_t)kk * Hh];
    float4 wv = *(const float4*)&scwq[half * 64 + kk][0];
    o0 = fmaf(wv.x, d, o0); o1 = fmaf(wv.y, d, o1);
    o2 = fmaf(wv.z, d, o2); o3 = fmaf(wv.w, d, o3);
  }
  ored[half][0][h] = o0; ored[half][1][h] = o1;
  ored[half][2][h] = o2; ored[half][3][h] = o3;
  __syncthreads();
  if (tid < Ll) {
#pragma unroll
    for (int jv = 0; jv < 4; ++jv)
      out[((size_t)n * Ll + jq * 4 + jv) * Hh + tid] = ored[0][jv][tid] + ored[1][jv][tid];
  }
}

extern "C" void kernel_launch(void* const* d_in, const int* in_sizes, int n_in,
                              void* d_out, int out_size, void* d_ws, size_t ws_size,
                              hipStream_t stream) {
  const float* wei   = (const float*)d_in[0];
  const int*   wmask = (const int*)d_in[1];
  const float* doc   = (const float*)d_in[2];
  const int*   dmask = (const int*)d_in[3];
  const float* q     = (const float*)d_in[4];
  const float* W1    = (const float*)d_in[5];
  const float* b1    = (const float*)d_in[6];
  const float* w2    = (const float*)d_in[7];
  const float* b2    = (const float*)d_in[8];
  float* out = (float*)d_out;

  float* ws = (float*)d_ws;
  float*          Bt   = ws;                                        // N*L*H fp32 (2.10 MB), b1 folded
  unsigned short* Ctb  = (unsigned short*)(Bt + (size_t)Nn * Ll * Hh);   // N*L*H bf16 (1.05 MB)
  short*          docb = (short*)(Ctb + (size_t)Nn * Ll * Hh);      // N*L*H bf16 (1.05 MB) => 4.19 MB total

  k_prep<<<2 * Nn, 256, 0, stream>>>(wei, wmask, doc, q, W1, b1, Bt, Ctb, docb);
  k_main<<<Nn * Ll / 4, 256, 0, stream>>>(doc, dmask, W1, w2, b2, Bt, Ctb, docb, out);
}